// Round 5
// baseline (313.229 us; speedup 1.0000x reference)
//
#include <hip/hip_runtime.h>

#define B_   4
#define S_   256
#define E_   256
#define H_   8
#define LD_  128
#define N_   65536
#define NC_  2

typedef __attribute__((ext_vector_type(8))) short s8v;   // 8 bf16
typedef __attribute__((ext_vector_type(4))) float f32x4;

__device__ __forceinline__ short f2bf(float f) {
  union { float f; unsigned u; } v; v.f = f;
  unsigned r = (v.u + 0x7FFFu + ((v.u >> 16) & 1u)) >> 16;   // RNE
  return (short)r;
}
__device__ __forceinline__ float bf2f(short s) {
  union { float f; unsigned u; } v; v.u = ((unsigned)(unsigned short)s) << 16;
  return v.f;
}
__device__ __forceinline__ s8v pack8(float4 a, float4 b) {
  s8v r;
  r[0] = f2bf(a.x); r[1] = f2bf(a.y); r[2] = f2bf(a.z); r[3] = f2bf(a.w);
  r[4] = f2bf(b.x); r[5] = f2bf(b.y); r[6] = f2bf(b.z); r[7] = f2bf(b.w);
  return r;
}

// ---------------------------------------------------------------------------
// prep_k: weight cvt/split + bn fold | ids fill | pos-MLP + gl^T -> Xhi/Xlo
// ---------------------------------------------------------------------------
__global__ __launch_bounds__(256) void prep_k(
    const int* __restrict__ npc, int* __restrict__ ids,
    const float* __restrict__ ipw, const float* __restrict__ opw,
    const float* __restrict__ w2, const float* __restrict__ w3,
    const float* __restrict__ b2, const float* __restrict__ g2,
    const float* __restrict__ be2, const float* __restrict__ mu2,
    const float* __restrict__ va2,
    const float* __restrict__ b3, const float* __restrict__ g3,
    const float* __restrict__ be3, const float* __restrict__ mu3,
    const float* __restrict__ va3,
    short* __restrict__ iph, short* __restrict__ ipl,
    short* __restrict__ oph, short* __restrict__ opl,
    short* __restrict__ w2bf, short* __restrict__ w3bf,
    float* __restrict__ sc2, float* __restrict__ sh2,
    float* __restrict__ sc3, float* __restrict__ sh3,
    const float* __restrict__ gl, const float* __restrict__ cen,
    const float* __restrict__ fc1w, const float* __restrict__ fc1b,
    const float* __restrict__ fc2w, const float* __restrict__ fc2b,
    short* __restrict__ Xhi, short* __restrict__ Xlo) {
  __shared__ int red[256];
  __shared__ float hsh[16];
  int bid = blockIdx.x, t = threadIdx.x;
  if (bid < 768) {
    int i = bid * 256 + t;
    if (i < 196608) {
      float v = ipw[i]; short h = f2bf(v);
      iph[i] = h; ipl[i] = f2bf(v - bf2f(h));
    }
    if (i < 65536) {
      float v = opw[i]; short h = f2bf(v);
      oph[i] = h; opl[i] = f2bf(v - bf2f(h));
    }
    if (i < 49152) w2bf[i] = f2bf(w2[i]);
    if (i < 8192)  w3bf[i] = f2bf(w3[i]);
    if (i < 128) {
      float sc = g2[i] * rsqrtf(va2[i] + 1e-5f);
      sc2[i] = sc; sh2[i] = (b2[i] - mu2[i]) * sc + be2[i];
    }
    if (i < 64) {
      float sc = g3[i] * rsqrtf(va3[i] + 1e-5f);
      sc3[i] = sc; sh3[i] = (b3[i] - mu3[i]) * sc + be3[i];
    }
  } else if (bid <= 1024) {
    int s = bid - 768;   // 0..256
    int val = (s == 256) ? npc[t] : ((t < s) ? npc[t] : 0);
    red[t] = val;
    __syncthreads();
    for (int off = 128; off > 0; off >>= 1) {
      if (t < off) red[t] += red[t + off];
      __syncthreads();
    }
    int st = red[0];
    if (s < 256) {
      int en = st + npc[s]; if (en > N_) en = N_;
      for (int n = st + t; n < en; n += 256) ids[n] = s;
    } else {
      for (int n = st + t; n < N_; n += 256) ids[n] = 255;
    }
  } else {
    int bs = bid - 1025;   // 0..1023
    int b = bs >> 8, s = bs & 255;
    if (t < 16) {
      float c0 = cen[bs * 2 + 0], c1 = cen[bs * 2 + 1];
      float v = c0 * fc1w[2 * t] + c1 * fc1w[2 * t + 1] + fc1b[t];
      hsh[t] = (v >= 0.f) ? v : 0.01f * v;
    }
    __syncthreads();
    float p = fc2b[t];
#pragma unroll
    for (int j = 0; j < 16; j++) p += hsh[j] * fc2w[t * 16 + j];
    float v = gl[((size_t)s * B_ + b) * E_ + t] + p;
    short h = f2bf(v);
    Xhi[(size_t)bs * E_ + t] = h;
    Xlo[(size_t)bs * E_ + t] = f2bf(v - bf2f(h));
  }
}

// ---------------------------------------------------------------------------
// bf16x3 MFMA GEMM (qkv): C = (Ah+Al)(Wh+Wl)^T + bias
// ---------------------------------------------------------------------------
__global__ __launch_bounds__(256) void gemm_x3_k(
    const short* __restrict__ Ah, const short* __restrict__ Al,
    const short* __restrict__ Wh, const short* __restrict__ Wl,
    const float* __restrict__ bias, float* __restrict__ Cf,
    int M, int N, int K) {
  __shared__ __align__(16) short gs[18432];
  const int AH = 0, AL = 4608, WH = 9216, WL = 13824;
  int t = threadIdx.x;
  int row0 = blockIdx.x * 64, col0 = blockIdx.y * 64;
  int w = t >> 6, l = t & 63, quad = l >> 4, lr = l & 15;
  int m0 = w * 16;
  int ar = t >> 2, aq = (t & 3) * 16;
  f32x4 acc[4];
#pragma unroll
  for (int i = 0; i < 4; i++) acc[i] = (f32x4)(0.f);

  for (int kc = 0; kc < K; kc += 64) {
    __syncthreads();
    {
      size_t ra = (size_t)(row0 + ar) * K + kc + aq;
      size_t rw = (size_t)(col0 + ar) * K + kc + aq;
      *(s8v*)&gs[AH + ar * 72 + aq]     = *(const s8v*)&Ah[ra];
      *(s8v*)&gs[AH + ar * 72 + aq + 8] = *(const s8v*)&Ah[ra + 8];
      *(s8v*)&gs[AL + ar * 72 + aq]     = *(const s8v*)&Al[ra];
      *(s8v*)&gs[AL + ar * 72 + aq + 8] = *(const s8v*)&Al[ra + 8];
      *(s8v*)&gs[WH + ar * 72 + aq]     = *(const s8v*)&Wh[rw];
      *(s8v*)&gs[WH + ar * 72 + aq + 8] = *(const s8v*)&Wh[rw + 8];
      *(s8v*)&gs[WL + ar * 72 + aq]     = *(const s8v*)&Wl[rw];
      *(s8v*)&gs[WL + ar * 72 + aq + 8] = *(const s8v*)&Wl[rw + 8];
    }
    __syncthreads();
#pragma unroll
    for (int ks = 0; ks < 2; ks++) {
      int ko = ks * 32 + quad * 8;
      s8v ah = *(const s8v*)&gs[AH + (m0 + lr) * 72 + ko];
      s8v al = *(const s8v*)&gs[AL + (m0 + lr) * 72 + ko];
#pragma unroll
      for (int ct = 0; ct < 4; ct++) {
        s8v bh = *(const s8v*)&gs[WH + (ct * 16 + lr) * 72 + ko];
        s8v bl = *(const s8v*)&gs[WL + (ct * 16 + lr) * 72 + ko];
        acc[ct] = __builtin_amdgcn_mfma_f32_16x16x32_bf16(ah, bh, acc[ct], 0, 0, 0);
        acc[ct] = __builtin_amdgcn_mfma_f32_16x16x32_bf16(al, bh, acc[ct], 0, 0, 0);
        acc[ct] = __builtin_amdgcn_mfma_f32_16x16x32_bf16(ah, bl, acc[ct], 0, 0, 0);
      }
    }
  }
#pragma unroll
  for (int ct = 0; ct < 4; ct++) {
    int c = col0 + ct * 16 + lr;
    float bb = bias[c];
#pragma unroll
    for (int rg = 0; rg < 4; rg++) {
      int r = row0 + m0 + quad * 4 + rg;
      Cf[(size_t)r * N + c] = acc[ct][rg] + bb;
    }
  }
}

// ---------------------------------------------------------------------------
// attention (unchanged)
// ---------------------------------------------------------------------------
__global__ __launch_bounds__(256) void attn_k(const float* __restrict__ qkv,
                                              short* __restrict__ Chi,
                                              short* __restrict__ Clo) {
  int bid = blockIdx.x;
  int qt = bid & 7, h = (bid >> 3) & 7, b = bid >> 6;
  __shared__ __align__(16) float smem[16384];
  float* Kx = smem;
  float* Vx = smem + 8192;
  int t = threadIdx.x;
#pragma unroll
  for (int i = 0; i < 8; i++) {
    int row = i * 32 + (t >> 3);
    int d4 = (t & 7) * 4;
    const float* base = qkv + (size_t)(b * S_ + row) * 768 + h * 32 + d4;
    *(float4*)&Kx[row * 32 + d4] = *(const float4*)(base + 256);
    *(float4*)&Vx[row * 32 + d4] = *(const float4*)(base + 512);
  }
  int r = t & 31, g = t >> 5;
  float q[32];
  {
    const float* qb = qkv + (size_t)(b * S_ + qt * 32 + r) * 768 + h * 32;
#pragma unroll
    for (int d4 = 0; d4 < 32; d4 += 4) {
      float4 v = *(const float4*)(qb + d4);
      q[d4] = v.x; q[d4 + 1] = v.y; q[d4 + 2] = v.z; q[d4 + 3] = v.w;
    }
  }
  __syncthreads();
  const float scale = 0.17677669529663687f;
  int kk0 = g * 32;
  float sc[32];
  float m = -1e30f;
#pragma unroll
  for (int kk = 0; kk < 32; kk++) {
    const float* kr = &Kx[(kk0 + kk) * 32];
    float4 a = (float4){0.f, 0.f, 0.f, 0.f};
#pragma unroll
    for (int d4 = 0; d4 < 32; d4 += 4) {
      float4 kv = *(const float4*)(kr + d4);
      a.x += q[d4] * kv.x; a.y += q[d4 + 1] * kv.y;
      a.z += q[d4 + 2] * kv.z; a.w += q[d4 + 3] * kv.w;
    }
    float s = ((a.x + a.y) + (a.z + a.w)) * scale;
    sc[kk] = s;
    m = fmaxf(m, s);
  }
  float lsum = 0.f;
  float ctx[32];
#pragma unroll
  for (int d = 0; d < 32; d++) ctx[d] = 0.f;
#pragma unroll
  for (int kk = 0; kk < 32; kk++) {
    const float* vr = &Vx[(kk0 + kk) * 32];
    float p = __expf(sc[kk] - m);
    lsum += p;
#pragma unroll
    for (int d4 = 0; d4 < 32; d4 += 4) {
      float4 vv = *(const float4*)(vr + d4);
      ctx[d4] += p * vv.x; ctx[d4 + 1] += p * vv.y;
      ctx[d4 + 2] += p * vv.z; ctx[d4 + 3] += p * vv.w;
    }
  }
  __syncthreads();
  float* ctxbuf = smem;
  float* mbuf = smem + 8192;
  float* lbuf = smem + 8448;
  mbuf[g * 32 + r] = m;
  lbuf[g * 32 + r] = lsum;
#pragma unroll
  for (int d = 0; d < 32; d++)
    ctxbuf[(g * 32 + r) * 32 + ((d + r) & 31)] = ctx[d];
  __syncthreads();
  int r2 = t & 31, dq = t >> 5;
  float M = -1e30f;
#pragma unroll
  for (int gg = 0; gg < 8; gg++) M = fmaxf(M, mbuf[gg * 32 + r2]);
  float wg[8]; float L = 0.f;
#pragma unroll
  for (int gg = 0; gg < 8; gg++) {
    wg[gg] = __expf(mbuf[gg * 32 + r2] - M);
    L += lbuf[gg * 32 + r2] * wg[gg];
  }
  float invL = 1.f / L;
  size_t base = (size_t)(b * S_ + qt * 32 + r2) * E_ + h * 32;
#pragma unroll
  for (int dd = 0; dd < 4; dd++) {
    int d = dq * 4 + dd;
    float o = 0.f;
#pragma unroll
    for (int gg = 0; gg < 8; gg++)
      o += ctxbuf[(gg * 32 + r2) * 32 + ((d + r2) & 31)] * wg[gg];
    o *= invL;
    short hi = f2bf(o);
    Chi[base + d] = hi;
    Clo[base + d] = f2bf(o - bf2f(hi));
  }
}

// ---------------------------------------------------------------------------
// opg_k: fused out_proj (bf16x3) + G = attn_out @ W2b^T.
// 64 blocks x 16 rows (4x the parallelism of round 4).
// Phase 1 LDS: AH[16][72] AL[16][72] WH[256][72] WL[256][72] = 78336 B.
// Phase 2 overlays: CT[16][264] @0, W2B[128][264] @4352.
// ---------------------------------------------------------------------------
__global__ __launch_bounds__(256) void opg_k(
    const short* __restrict__ Chi, const short* __restrict__ Clo,
    const short* __restrict__ oph, const short* __restrict__ opl,
    const float* __restrict__ opb, const short* __restrict__ w2bf,
    float* __restrict__ G) {
  __shared__ __align__(16) short gsm[39168];   // 78336 B
  const int AH = 0, AL = 1152, WH = 2304, WL = 20736;  // phase 1 (shorts)
  const int CT = 0, W2B = 4352;                         // phase 2 (shorts)
  int t = threadIdx.x;
  int row0 = blockIdx.x * 16;
  int w = t >> 6, l = t & 63, quad = l >> 4, lr = l & 15;

  f32x4 acc[4];
#pragma unroll
  for (int i = 0; i < 4; i++) acc[i] = (f32x4)(0.f);

  for (int kc = 0; kc < 256; kc += 64) {
    __syncthreads();
    {  // W: 256 rows x 64 k (hi+lo)
#pragma unroll
      for (int j = 0; j < 8; j++) {
        *(s8v*)&gsm[WH + t * 72 + j * 8] = *(const s8v*)&oph[(size_t)t * 256 + kc + j * 8];
        *(s8v*)&gsm[WL + t * 72 + j * 8] = *(const s8v*)&opl[(size_t)t * 256 + kc + j * 8];
      }
      // A: 16 rows x 64 k (hi+lo)
      if (t < 32) {
        int row = t >> 1, half = (t & 1) * 32;
        size_t ra = (size_t)(row0 + row) * 256 + kc + half;
#pragma unroll
        for (int j = 0; j < 4; j++) {
          *(s8v*)&gsm[AH + row * 72 + half + j * 8] = *(const s8v*)&Chi[ra + j * 8];
          *(s8v*)&gsm[AL + row * 72 + half + j * 8] = *(const s8v*)&Clo[ra + j * 8];
        }
      }
    }
    __syncthreads();
#pragma unroll
    for (int ks = 0; ks < 2; ks++) {
      int ko = ks * 32 + quad * 8;
      s8v ah = *(const s8v*)&gsm[AH + lr * 72 + ko];
      s8v al = *(const s8v*)&gsm[AL + lr * 72 + ko];
#pragma unroll
      for (int ct = 0; ct < 4; ct++) {
        s8v bh = *(const s8v*)&gsm[WH + (w * 64 + ct * 16 + lr) * 72 + ko];
        s8v bl = *(const s8v*)&gsm[WL + (w * 64 + ct * 16 + lr) * 72 + ko];
        acc[ct] = __builtin_amdgcn_mfma_f32_16x16x32_bf16(ah, bh, acc[ct], 0, 0, 0);
        acc[ct] = __builtin_amdgcn_mfma_f32_16x16x32_bf16(al, bh, acc[ct], 0, 0, 0);
        acc[ct] = __builtin_amdgcn_mfma_f32_16x16x32_bf16(ah, bl, acc[ct], 0, 0, 0);
      }
    }
  }
  __syncthreads();
  // attn_out tile -> CT (bf16); stage W2b (w2 cols 128..383)
#pragma unroll
  for (int ct = 0; ct < 4; ct++) {
    int c = w * 64 + ct * 16 + lr;
    float bb = opb[c];
#pragma unroll
    for (int rg = 0; rg < 4; rg++) {
      int r = quad * 4 + rg;
      gsm[CT + r * 264 + c] = f2bf(acc[ct][rg] + bb);
    }
  }
  {
    int ch = t >> 1, koff = (t & 1) * 128;
#pragma unroll
    for (int j = 0; j < 16; j++)
      *(s8v*)&gsm[W2B + ch * 264 + koff + j * 8] =
          *(const s8v*)&w2bf[(size_t)ch * 384 + 128 + koff + j * 8];
  }
  __syncthreads();
  // G[16][128] = CT @ W2B^T; wave w covers channels w*32..w*32+32
  f32x4 acc2[2];
#pragma unroll
  for (int i = 0; i < 2; i++) acc2[i] = (f32x4)(0.f);
#pragma unroll
  for (int ks = 0; ks < 8; ks++) {
    int ko = ks * 32 + quad * 8;
    s8v a = *(const s8v*)&gsm[CT + lr * 264 + ko];
#pragma unroll
    for (int cc = 0; cc < 2; cc++) {
      s8v b = *(const s8v*)&gsm[W2B + (w * 32 + cc * 16 + lr) * 264 + ko];
      acc2[cc] = __builtin_amdgcn_mfma_f32_16x16x32_bf16(a, b, acc2[cc], 0, 0, 0);
    }
  }
#pragma unroll
  for (int cc = 0; cc < 2; cc++) {
    int c = w * 32 + cc * 16 + lr;
#pragma unroll
    for (int rg = 0; rg < 4; rg++) {
      int r = row0 + quad * 4 + rg;
      G[(size_t)r * 128 + c] = acc2[cc][rg];
    }
  }
}

// ---------------------------------------------------------------------------
// conv_fused: conv2 (K=128) + G-gather + bn2/relu -> conv3 (W3 from global/L1)
// -> conv4. Block = 128 pts, 4 waves. LDS 36864+512 B -> 4 blocks/CU.
// ---------------------------------------------------------------------------
#define CV_SA  0        // [128][72] shorts
#define CV_SW  9216     // [128][72] shorts
#define CV_H2  0        // [128][136] shorts (overlays SA+SW after conv2)
#define CV_H3  0        // [128][72] (over H2 after conv3)

__global__ __launch_bounds__(256, 4) void conv_fused_k(
    const float* __restrict__ lo, const float* __restrict__ G,
    const int* __restrict__ ids,
    const short* __restrict__ w2bf, const short* __restrict__ w3bf,
    const float* __restrict__ sc2, const float* __restrict__ sh2,
    const float* __restrict__ sc3, const float* __restrict__ sh3,
    const float* __restrict__ w4, const float* __restrict__ b4,
    float* __restrict__ out) {
  __shared__ __align__(16) short smem[18432];  // 36864 B
  __shared__ int lds_ids[128];
  int t = threadIdx.x;
  int bid = blockIdx.x;
  int b = bid >> 9;
  int n0 = (bid & 511) << 7;
  int w = t >> 6, l = t & 63;
  int quad = l >> 4, lr = l & 15;
  int mh = w & 1, chh = w >> 1;
  int ar = t >> 1, akh = (t & 1) * 32;
  const float* lob = &lo[((size_t)b * N_ + n0 + ar) * LD_ + akh];
  const short* wb  = &w2bf[(size_t)ar * 384 + akh];

  if (t < 128) lds_ids[t] = ids[n0 + t];

  f32x4 acc2[4][4];
#pragma unroll
  for (int i = 0; i < 4; i++)
#pragma unroll
    for (int j = 0; j < 4; j++) acc2[i][j] = (f32x4)(0.f);

  // ---- conv2: K = 128 in 2 chunks of 64 (single-buffer, rely on 16-wave TLP)
  for (int kc = 0; kc < 2; kc++) {
    if (kc) __syncthreads();   // protect previous chunk's reads
    {
      float4 v0, v1;
#pragma unroll
      for (int j = 0; j < 4; j++) {
        v0 = *(const float4*)(lob + kc * 64 + j * 8);
        v1 = *(const float4*)(lob + kc * 64 + j * 8 + 4);
        *(s8v*)&smem[CV_SA + ar * 72 + akh + j * 8] = pack8(v0, v1);
      }
#pragma unroll
      for (int j = 0; j < 4; j++)
        *(s8v*)&smem[CV_SW + ar * 72 + akh + j * 8] = *(const s8v*)(wb + kc * 64 + j * 8);
    }
    __syncthreads();
#pragma unroll
    for (int ks = 0; ks < 2; ks++) {
      int ko = ks * 32 + quad * 8;
      s8v af[4], bf[4];
#pragma unroll
      for (int mt = 0; mt < 4; mt++)
        af[mt] = *(const s8v*)&smem[CV_SA + (64 * mh + 16 * mt + lr) * 72 + ko];
#pragma unroll
      for (int ct = 0; ct < 4; ct++)
        bf[ct] = *(const s8v*)&smem[CV_SW + (64 * chh + 16 * ct + lr) * 72 + ko];
#pragma unroll
      for (int mt = 0; mt < 4; mt++)
#pragma unroll
        for (int ct = 0; ct < 4; ct++)
          acc2[mt][ct] = __builtin_amdgcn_mfma_f32_16x16x32_bf16(af[mt], bf[ct], acc2[mt][ct], 0, 0, 0);
    }
  }
  __syncthreads();  // SA/SW dead

  // ---- epilogue: gather G (per-mt, low reg pressure), bn2+relu -> H2
#pragma unroll
  for (int ct = 0; ct < 4; ct++) {
    int c = 64 * chh + 16 * ct + lr;
    float sc = sc2[c], sh = sh2[c];
#pragma unroll
    for (int mt = 0; mt < 4; mt++) {
      float gv[4];
#pragma unroll
      for (int rg = 0; rg < 4; rg++) {
        int p = 64 * mh + 16 * mt + 4 * quad + rg;
        gv[rg] = G[((size_t)b * 256 + lds_ids[p]) * 128 + c];
      }
#pragma unroll
      for (int rg = 0; rg < 4; rg++) {
        int p = 64 * mh + 16 * mt + 4 * quad + rg;
        float z = (acc2[mt][ct][rg] + gv[rg]) * sc + sh;
        smem[CV_H2 + p * 136 + c] = f2bf(fmaxf(z, 0.f));
      }
    }
  }
  __syncthreads();

  // ---- conv3: 128 pts x 64 ch, K=128; W3 fragments from global (L1-resident)
  f32x4 acc3[2][4];
#pragma unroll
  for (int i = 0; i < 2; i++)
#pragma unroll
    for (int j = 0; j < 4; j++) acc3[i][j] = (f32x4)(0.f);
#pragma unroll
  for (int ks = 0; ks < 4; ks++) {
    int ko = ks * 32 + quad * 8;
    s8v af[2], bf[4];
#pragma unroll
    for (int mt = 0; mt < 2; mt++)
      af[mt] = *(const s8v*)&smem[CV_H2 + (32 * w + 16 * mt + lr) * 136 + ko];
#pragma unroll
    for (int ct = 0; ct < 4; ct++)
      bf[ct] = *(const s8v*)&w3bf[(size_t)(16 * ct + lr) * 128 + ko];
#pragma unroll
    for (int mt = 0; mt < 2; mt++)
#pragma unroll
      for (int ct = 0; ct < 4; ct++)
        acc3[mt][ct] = __builtin_amdgcn_mfma_f32_16x16x32_bf16(af[mt], bf[ct], acc3[mt][ct], 0, 0, 0);
  }
  __syncthreads();  // H2 reads done before H3 overlay

  // ---- bn3 + relu -> H3
#pragma unroll
  for (int ct = 0; ct < 4; ct++) {
    int c = 16 * ct + lr;
    float sc = sc3[c], sh = sh3[c];
#pragma unroll
    for (int mt = 0; mt < 2; mt++)
#pragma unroll
      for (int rg = 0; rg < 4; rg++) {
        int p = 32 * w + 16 * mt + 4 * quad + rg;
        float z = acc3[mt][ct][rg] * sc + sh;
        smem[CV_H3 + p * 72 + c] = f2bf(fmaxf(z, 0.f));
      }
  }
  __syncthreads();

  // ---- conv4 (fp32)
  {
    int c = t >> 7, p = t & 127;
    float s = b4[c];
#pragma unroll
    for (int j = 0; j < 8; j++) {
      s8v hv = *(const s8v*)&smem[CV_H3 + p * 72 + j * 8];
#pragma unroll
      for (int e = 0; e < 8; e++)
        s += bf2f(hv[e]) * w4[c * 64 + j * 8 + e];
    }
    out[((size_t)b * NC_ + c) * N_ + n0 + p] = s;
  }
}

// ---------------------------------------------------------------------------
extern "C" void kernel_launch(void* const* d_in, const int* in_sizes, int n_in,
                              void* d_out, int out_size, void* d_ws, size_t ws_size,
                              hipStream_t stream) {
  const float* gl   = (const float*)d_in[0];
  const float* lo   = (const float*)d_in[1];
  const float* cen  = (const float*)d_in[2];
  const int*   npc  = (const int*)d_in[3];
  const float* fc1w = (const float*)d_in[4];
  const float* fc1b = (const float*)d_in[5];
  const float* fc2w = (const float*)d_in[6];
  const float* fc2b = (const float*)d_in[7];
  const float* ipw  = (const float*)d_in[8];
  const float* ipb  = (const float*)d_in[9];
  const float* opw  = (const float*)d_in[10];
  const float* opb  = (const float*)d_in[11];
  const float* w2   = (const float*)d_in[12];
  const float* b2   = (const float*)d_in[13];
  const float* g2   = (const float*)d_in[14];
  const float* be2  = (const float*)d_in[15];
  const float* mu2  = (const float*)d_in[16];
  const float* va2  = (const float*)d_in[17];
  const float* w3   = (const float*)d_in[18];
  const float* b3   = (const float*)d_in[19];
  const float* g3   = (const float*)d_in[20];
  const float* be3  = (const float*)d_in[21];
  const float* mu3  = (const float*)d_in[22];
  const float* va3  = (const float*)d_in[23];
  const float* w4   = (const float*)d_in[24];
  const float* b4   = (const float*)d_in[25];

  char* ws = (char*)d_ws;
  float* qkv  = (float*)(ws);                  // 3,145,728
  short* Xhi  = (short*)(ws + 3145728);        // 524,288
  short* Xlo  = (short*)(ws + 3670016);
  short* Chi  = (short*)(ws + 4194304);
  short* Clo  = (short*)(ws + 4718592);
  float* G    = (float*)(ws + 5242880);        // 524,288 (B,256,128) fp32
  short* iph  = (short*)(ws + 5767168);        // 393,216
  short* ipl  = (short*)(ws + 6160384);
  short* oph  = (short*)(ws + 6553600);        // 131,072
  short* opl  = (short*)(ws + 6684672);
  short* w2bf = (short*)(ws + 6815744);        // 98,304
  short* w3bf = (short*)(ws + 6914048);        // 16,384
  int*   ids  = (int*)  (ws + 6930432);        // 262,144
  float* sc2  = (float*)(ws + 7192576);
  float* sh2  = (float*)(ws + 7193088);
  float* sc3  = (float*)(ws + 7193600);
  float* sh3  = (float*)(ws + 7193856);
  float* out  = (float*)d_out;

  prep_k<<<2049, 256, 0, stream>>>(npc, ids, ipw, opw, w2, w3,
                                   b2, g2, be2, mu2, va2,
                                   b3, g3, be3, mu3, va3,
                                   iph, ipl, oph, opl, w2bf, w3bf,
                                   sc2, sh2, sc3, sh3,
                                   gl, cen, fc1w, fc1b, fc2w, fc2b, Xhi, Xlo);
  gemm_x3_k<<<dim3(16, 12), 256, 0, stream>>>(Xhi, Xlo, iph, ipl, ipb,
                                              qkv, B_ * S_, 768, E_);
  attn_k<<<B_ * H_ * 8, 256, 0, stream>>>(qkv, Chi, Clo);
  opg_k<<<64, 256, 0, stream>>>(Chi, Clo, oph, opl, opb, w2bf, G);
  conv_fused_k<<<B_ * (N_ / 128), 256, 0, stream>>>(
      lo, G, ids, w2bf, w3bf, sc2, sh2, sc3, sh3, w4, b4, out);
}